// Round 6
// baseline (1061.217 us; speedup 1.0000x reference)
//
#include <hip/hip_runtime.h>
#include <cmath>

// Problem constants
#define M 256
#define N 512
#define P 24
#define D 8

// ---------------------------------------------------------------------------
// self terms + folded weights at[i,u] = A[i,u]*exp(-0.5*||x_iu||^2).
// Block M+N writes the ones-column of Bc.
// ---------------------------------------------------------------------------
__global__ __launch_bounds__(64) void self_kernel(const float* __restrict__ X_test,
                                                  const float* __restrict__ A_test,
                                                  const float* __restrict__ X_obs,
                                                  const float* __restrict__ A_obs,
                                                  float* __restrict__ s1,
                                                  float* __restrict__ s2,
                                                  float* __restrict__ atT,
                                                  float* __restrict__ atO,
                                                  double* __restrict__ Bc) {
    const int bid = blockIdx.x;
    const int lane = threadIdx.x;
    if (bid == M + N) {  // ones column (col 256 of Bc, col-major [257][512])
#pragma unroll
        for (int t = 0; t < 8; ++t) Bc[(size_t)256 * 512 + 64 * t + lane] = 1.0;
        return;
    }
    const float* X; const float* A; float* s; float* at; int i;
    if (bid < M) { X = X_test; A = A_test; s = s1; at = atT; i = bid; }
    else         { X = X_obs;  A = A_obs;  s = s2; at = atO; i = bid - M; }
    const float* Xi = X + (size_t)i * P * D;
    const float* Ai = A + (size_t)i * P;
    float acc = 0.f;
#pragma unroll
    for (int t = 0; t < 9; ++t) {
        int idx = lane + 64 * t;          // 0..575
        int u = idx / 24;
        int v = idx - u * 24;
        const float* xu = Xi + u * D;
        const float* xv = Xi + v * D;
        float d2 = 0.f;
#pragma unroll
        for (int d = 0; d < D; ++d) { float df = xu[d] - xv[d]; d2 = fmaf(df, df, d2); }
        acc = fmaf(Ai[u] * Ai[v], __expf(-0.5f * d2), acc);
    }
#pragma unroll
    for (int off = 1; off < 64; off <<= 1) acc += __shfl_xor(acc, off, 64);
    if (lane == 0) s[i] = acc;
    if (lane < 24) {
        const float* xp = Xi + lane * D;
        float q = 0.f;
#pragma unroll
        for (int d = 0; d < D; ++d) q = fmaf(xp[d], xp[d], q);
        at[(size_t)i * P + lane] = Ai[lane] * __expf(-0.5f * q);
    }
}

// ---------------------------------------------------------------------------
// fused gram kernel with norm-folded weights (unchanged from r5)
// ---------------------------------------------------------------------------
__global__ __launch_bounds__(128) void gram_kernel(
    const float* __restrict__ Xt, const float* __restrict__ atT, const float* __restrict__ s1,
    const float* __restrict__ Xo, const float* __restrict__ atO, const float* __restrict__ s2,
    const float* __restrict__ rho_p, const float* __restrict__ nu_p, const float* __restrict__ g_p,
    float* __restrict__ Kox, float* __restrict__ Kxx, double* __restrict__ Koo,
    double* __restrict__ Bc) {
    const int mode = blockIdx.z;
    const int it = blockIdx.x, jt = blockIdx.y;
    const float *X1, *AT1, *S1, *X2, *AT2, *S2;
    if (mode == 0) {
        if (jt > 2 * it + 1) return;
        X1 = Xo; AT1 = atO; S1 = s2; X2 = Xo; AT2 = atO; S2 = s2;
    } else if (mode == 1) {
        if (jt >= 32) return;
        X1 = Xo; AT1 = atO; S1 = s2; X2 = Xt; AT2 = atT; S2 = s1;
    } else {
        if (it >= 16 || jt >= 32 || jt < 2 * it) return;
        X1 = Xt; AT1 = atT; S1 = s1; X2 = Xt; AT2 = atT; S2 = s1;
    }
    const int i0 = it * 16, j0 = jt * 8;
    const int tid = threadIdx.x;
    const int il = tid >> 3, uc = tid & 7;
    const int i = i0 + il;

    __shared__ __align__(16) float X2s[8 * 192];
    __shared__ float A2s[8 * 24];
    __shared__ float S2s[8];
    {
        const float4* gx = (const float4*)(X2 + (size_t)j0 * 192);
        float4* lx = (float4*)X2s;
        for (int idx = tid; idx < 8 * 48; idx += 128) lx[idx] = gx[idx];
        for (int idx = tid; idx < 8 * 24; idx += 128) A2s[idx] = AT2[(size_t)j0 * 24 + idx];
        if (tid < 8) S2s[tid] = S2[j0 + tid];
    }
    __syncthreads();

    float x1r[3][8], at1r[3];
#pragma unroll
    for (int ss = 0; ss < 3; ++ss) {
        const float* p = X1 + ((size_t)i * P + uc * 3 + ss) * D;
#pragma unroll
        for (int d = 0; d < D; ++d) x1r[ss][d] = p[d];
        at1r[ss] = AT1[(size_t)i * P + uc * 3 + ss];
    }
    const float s1i = S1[i];
    const float rho = rho_p[0], nu = nu_p[0], g = g_p[0];

    for (int jj = 0; jj < 8; ++jj) {
        const float* xb = X2s + jj * 192;
        float e0 = 0.f, e1 = 0.f, e2 = 0.f;
#pragma unroll 4
        for (int v = 0; v < 24; ++v) {
            const float4 q0 = ((const float4*)(xb + v * 8))[0];
            const float4 q1 = ((const float4*)(xb + v * 8))[1];
            float x2r[8];
            x2r[0] = q0.x; x2r[1] = q0.y; x2r[2] = q0.z; x2r[3] = q0.w;
            x2r[4] = q1.x; x2r[5] = q1.y; x2r[6] = q1.z; x2r[7] = q1.w;
            const float w2 = A2s[jj * 24 + v];
            float d0 = 0.f, d1 = 0.f, d2 = 0.f;
#pragma unroll
            for (int dd = 0; dd < 8; ++dd) {
                d0 = fmaf(x1r[0][dd], x2r[dd], d0);
                d1 = fmaf(x1r[1][dd], x2r[dd], d1);
                d2 = fmaf(x1r[2][dd], x2r[dd], d2);
            }
            e0 = fmaf(w2, __expf(d0), e0);
            e1 = fmaf(w2, __expf(d1), e1);
            e2 = fmaf(w2, __expf(d2), e2);
        }
        float acc = at1r[0] * e0;
        acc = fmaf(at1r[1], e1, acc);
        acc = fmaf(at1r[2], e2, acc);
        acc += __shfl_xor(acc, 1, 8);
        acc += __shfl_xor(acc, 2, 8);
        acc += __shfl_xor(acc, 4, 8);
        if (uc == 0) {
            const int j = j0 + jj;
            float d2p = fmaxf(s1i + S2s[jj] - 2.f * acc, 0.f);
            float kv = __expf(-0.5f * d2p / rho);
            if (mode == 0) {
                if (j <= i) Koo[(size_t)i * 512 + j] = (double)(nu * (kv + ((i == j) ? g : 0.f)));
            } else if (mode == 1) {
                float val = nu * kv;
                Kox[(size_t)i * 256 + j] = val;
                Bc[(size_t)j * 512 + i] = (double)val;
            } else {
                float val = nu * kv;
                if (j >= i) {
                    Kxx[(size_t)i * 256 + j] = val;
                    if (j > i) Kxx[(size_t)j * 256 + i] = val;
                }
            }
        }
    }
}

// ---------------------------------------------------------------------------
// factor64: factor a 64x64 SPD tile held in sA (lower, upper zeroed) and
// produce L (written to LT upper-transpose layout) and X = inv(L) into
// Dinv[p]/DinvT[p]. sX/sW are LDS scratch. Verified structure from r4/r5.
// ---------------------------------------------------------------------------
__device__ void factor64(double (*sA)[65], double (*sX)[65], double* sW,
                         double* __restrict__ LT,
                         double* __restrict__ Dinv,
                         double* __restrict__ DinvT,
                         int p) {
    const int tid = threadIdx.x;
    const int k0 = p * 64;
    {
        double* f = &sX[0][0];
        for (int idx = tid; idx < 64 * 65; idx += 256) f[idx] = 0.0;
    }
    __syncthreads();
    for (int q = 0; q < 4; ++q) {
        const int b0 = 16 * q;
        if (tid < 64) {
            // LDL deferred-scale sweep, in-order same-wave LDS
            for (int k = 0; k < 15; ++k) {
                double inv = 1.0 / sA[b0 + k][b0 + k];
#pragma unroll
                for (int t = 0; t < 4; ++t) {
                    int idx = tid + 64 * t, r = idx >> 4, c = idx & 15;
                    if (r > k && c > k && c <= r)
                        sA[b0 + r][b0 + c] -= sA[b0 + r][b0 + k] * sA[b0 + c][b0 + k] * inv;
                }
                asm volatile("" ::: "memory");
            }
            // scale to true L
            double dq = (tid < 16) ? sqrt(sA[b0 + tid][b0 + tid]) : 1.0;
            asm volatile("" ::: "memory");
#pragma unroll
            for (int t = 0; t < 4; ++t) {
                int idx = tid + 64 * t, r = idx >> 4, c = idx & 15;
                double dcol = __shfl(dq, c, 64);
                if (c <= r) sA[b0 + r][b0 + c] = (r == c) ? dcol : sA[b0 + r][b0 + c] / dcol;
            }
            asm volatile("" ::: "memory");
            // X_qq = inv(L_qq): 4 lanes per column
            int c = tid >> 2, qd = tid & 3;
            if (qd == 0) sX[b0 + c][b0 + c] = 1.0 / sA[b0 + c][b0 + c];
            asm volatile("" ::: "memory");
            for (int r = 1; r < 16; ++r) {
                double partial = 0.0;
                for (int t = c + qd; t < r; t += 4)
                    partial = fma(sA[b0 + r][b0 + t], sX[b0 + t][b0 + c], partial);
                partial += __shfl_xor(partial, 1, 4);
                partial += __shfl_xor(partial, 2, 4);
                if (qd == 0 && r > c)
                    sX[b0 + r][b0 + c] = -partial / sA[b0 + r][b0 + r];
                asm volatile("" ::: "memory");
            }
        }
        __syncthreads();
        if (q < 3) {
            const int nrows = 48 - b0;
            const int cells = nrows * 16;
            double tv[3];
#pragma unroll
            for (int ii = 0; ii < 3; ++ii) {
                int idx = tid + 256 * ii;
                tv[ii] = 0.0;
                if (idx < cells) {
                    int a = b0 + 16 + (idx >> 4), cc = idx & 15;
                    double acc = 0.0;
                    for (int t = 0; t <= cc; ++t)
                        acc = fma(sA[a][b0 + t], sX[b0 + cc][b0 + t], acc);
                    tv[ii] = acc;
                }
            }
            __syncthreads();
#pragma unroll
            for (int ii = 0; ii < 3; ++ii) {
                int idx = tid + 256 * ii;
                if (idx < cells) {
                    int a = b0 + 16 + (idx >> 4), cc = idx & 15;
                    sA[a][b0 + cc] = tv[ii];
                }
            }
            __syncthreads();
            for (int idx = tid; idx < nrows * nrows; idx += 256) {
                int r = b0 + 16 + idx / nrows, cc = b0 + 16 + idx % nrows;
                if (cc <= r) {
                    double acc = 0.0;
#pragma unroll
                    for (int t = 0; t < 16; ++t)
                        acc = fma(sA[r][b0 + t], sA[cc][b0 + t], acc);
                    sA[r][cc] -= acc;
                }
            }
            __syncthreads();
        }
    }
    // assemble off-diagonal 16x16 blocks of X = inv(L64): 3 levels
    for (int d = 1; d <= 3; ++d) {
        __syncthreads();
        int npairs = 4 - d;
        for (int i2 = tid; i2 < npairs * 256; i2 += 256) {
            int pr = i2 >> 8, cell = i2 & 255, r = cell >> 4, c = cell & 15;
            int qc = pr, qr = pr + d;
            double w = 0.0;
            for (int t = 16 * qc; t < 16 * qr; ++t)
                w = fma(sA[16 * qr + r][t], sX[t][16 * qc + c], w);
            sW[pr * 272 + r * 17 + c] = w;
        }
        __syncthreads();
        for (int i2 = tid; i2 < npairs * 256; i2 += 256) {
            int pr = i2 >> 8, cell = i2 & 255, r = cell >> 4, c = cell & 15;
            int qc = pr, qr = pr + d;
            double x = 0.0;
            for (int t = 0; t <= r; ++t)
                x = fma(sX[16 * qr + r][16 * qr + t], sW[pr * 272 + t * 17 + c], x);
            sX[16 * qr + r][16 * qc + c] = -x;
        }
    }
    __syncthreads();
    for (int idx = tid; idx < 4096; idx += 256) {
        int r = idx >> 6, c = idx & 63;
        if (c <= r) LT[(size_t)(k0 + c) * 512 + k0 + r] = sA[r][c];
        double xv = sX[r][c];
        Dinv[(size_t)p * 4096 + idx] = xv;
        DinvT[(size_t)p * 4096 + (size_t)c * 64 + r] = xv;
    }
}

// factor of panel 0 (separate tiny launch)
__global__ __launch_bounds__(256) void factor0_kernel(const double* __restrict__ A,
                                                      double* __restrict__ LT,
                                                      double* __restrict__ Dinv,
                                                      double* __restrict__ DinvT) {
    __shared__ double smem[2 * 64 * 65 + 816];
    double (*sA)[65] = (double(*)[65])smem;
    double (*sX)[65] = (double(*)[65])(smem + 64 * 65);
    double* sW = smem + 2 * 64 * 65;
    const int tid = threadIdx.x;
    for (int idx = tid; idx < 4096; idx += 256) {
        int r = idx >> 6, c = idx & 63;
        sA[r][c] = (c <= r) ? A[(size_t)r * 512 + c] : 0.0;
    }
    factor64(sA, sX, sW, LT, Dinv, DinvT, 0);  // first barrier inside covers load
}

// ---------------------------------------------------------------------------
// Fused trailing-update for panel p (one launch per panel; kernel boundary =
// barrier). Block (bi,bj) owns trailing tile (I,J), I=p+1+bi, J=p+1+bj, bj<=bi.
// Phase 1: recompute L_Ip = A_Ip * Dinv_p^T (and L_Jp). Diagonal blocks write
// L_Ip to LT. Phase 2: A_IJ -= L_Ip * L_Jp^T. The (0,0) block then factors
// panel p+1 in place (it already holds the updated diagonal tile).
// ---------------------------------------------------------------------------
__global__ __launch_bounds__(256) void upd_kernel(double* __restrict__ A,
                                                  double* __restrict__ LT,
                                                  double* __restrict__ Dinv,
                                                  double* __restrict__ DinvT,
                                                  int p) {
    __shared__ double smem[2 * 64 * 67 + 64 * 64];   // 101,376 B
    double (*sLi)[67] = (double(*)[67])smem;
    double (*sLj)[67] = (double(*)[67])(smem + 64 * 67);
    double (*sD)[64]  = (double(*)[64])(smem + 2 * 64 * 67);

    int s = blockIdx.x, bi = 0;
    while (s >= bi + 1) { s -= bi + 1; ++bi; }
    const int bj = s;
    const int I = p + 1 + bi, J = p + 1 + bj;
    const bool diag = (I == J);
    const int tid = threadIdx.x;
    const int tx = tid & 15, ty = tid >> 4;

    const double* Ati = A + (size_t)I * 64 * 512 + (size_t)p * 64;
    const double* Atj = A + (size_t)J * 64 * 512 + (size_t)p * 64;
    for (int idx = tid; idx < 4096; idx += 256) {
        int r = idx >> 6, c = idx & 63;
        sLi[r][c] = Ati[(size_t)r * 512 + c];
        if (!diag) sLj[r][c] = Atj[(size_t)r * 512 + c];
        sD[r][c] = DinvT[(size_t)p * 4096 + idx];
    }
    __syncthreads();

    // phase 1: lip = A_Ip * X^T, ljp = A_Jp * X^T  (sD[t][c] = X[c][t])
    double lip[4][4] = {}, ljp[4][4] = {};
    for (int t = 0; t < 64; ++t) {
        double b0 = sD[t][4 * tx + 0], b1 = sD[t][4 * tx + 1];
        double b2 = sD[t][4 * tx + 2], b3 = sD[t][4 * tx + 3];
#pragma unroll
        for (int r = 0; r < 4; ++r) {
            double a = sLi[4 * ty + r][t];
            lip[r][0] = fma(a, b0, lip[r][0]);
            lip[r][1] = fma(a, b1, lip[r][1]);
            lip[r][2] = fma(a, b2, lip[r][2]);
            lip[r][3] = fma(a, b3, lip[r][3]);
        }
        if (!diag) {
#pragma unroll
            for (int r = 0; r < 4; ++r) {
                double a = sLj[4 * ty + r][t];
                ljp[r][0] = fma(a, b0, ljp[r][0]);
                ljp[r][1] = fma(a, b1, ljp[r][1]);
                ljp[r][2] = fma(a, b2, ljp[r][2]);
                ljp[r][3] = fma(a, b3, ljp[r][3]);
            }
        }
    }
    __syncthreads();
#pragma unroll
    for (int r = 0; r < 4; ++r)
#pragma unroll
        for (int c = 0; c < 4; ++c) {
            sLi[4 * ty + r][4 * tx + c] = lip[r][c];
            if (!diag) sLj[4 * ty + r][4 * tx + c] = ljp[r][c];
        }
    if (diag) {  // L panel write (only consumer: solve, via LT)
#pragma unroll
        for (int r = 0; r < 4; ++r)
#pragma unroll
            for (int c = 0; c < 4; ++c)
                LT[(size_t)(p * 64 + 4 * tx + c) * 512 + (size_t)I * 64 + 4 * ty + r] = lip[r][c];
    }
    __syncthreads();

    // phase 2: acc = L_Ip * L_Jp^T
    double (*Bp)[67] = diag ? sLi : sLj;
    double acc[4][4] = {};
    for (int t = 0; t < 64; ++t) {
        double a0 = sLi[4 * ty + 0][t], a1 = sLi[4 * ty + 1][t];
        double a2 = sLi[4 * ty + 2][t], a3 = sLi[4 * ty + 3][t];
        double b0 = Bp[4 * tx + 0][t], b1 = Bp[4 * tx + 1][t];
        double b2 = Bp[4 * tx + 2][t], b3 = Bp[4 * tx + 3][t];
        acc[0][0] = fma(a0, b0, acc[0][0]); acc[0][1] = fma(a0, b1, acc[0][1]);
        acc[0][2] = fma(a0, b2, acc[0][2]); acc[0][3] = fma(a0, b3, acc[0][3]);
        acc[1][0] = fma(a1, b0, acc[1][0]); acc[1][1] = fma(a1, b1, acc[1][1]);
        acc[1][2] = fma(a1, b2, acc[1][2]); acc[1][3] = fma(a1, b3, acc[1][3]);
        acc[2][0] = fma(a2, b0, acc[2][0]); acc[2][1] = fma(a2, b1, acc[2][1]);
        acc[2][2] = fma(a2, b2, acc[2][2]); acc[2][3] = fma(a2, b3, acc[2][3]);
        acc[3][0] = fma(a3, b0, acc[3][0]); acc[3][1] = fma(a3, b1, acc[3][1]);
        acc[3][2] = fma(a3, b2, acc[3][2]); acc[3][3] = fma(a3, b3, acc[3][3]);
    }

    double* Aij = A + (size_t)I * 64 * 512 + (size_t)J * 64;
    if (bi == 0 && bj == 0) {
        // updated diagonal tile -> factor panel p+1 in place
        __syncthreads();
        double (*fA)[65] = (double(*)[65])smem;
        double (*fX)[65] = (double(*)[65])(smem + 64 * 65);
        double* fW = smem + 2 * 64 * 65;
#pragma unroll
        for (int r = 0; r < 4; ++r)
#pragma unroll
            for (int c = 0; c < 4; ++c) {
                int rr = 4 * ty + r, cc = 4 * tx + c;
                fA[rr][cc] = (cc <= rr) ? (Aij[(size_t)rr * 512 + cc] - acc[r][c]) : 0.0;
            }
        __syncthreads();
        factor64(fA, fX, fW, LT, Dinv, DinvT, p + 1);
    } else {
#pragma unroll
        for (int r = 0; r < 4; ++r)
#pragma unroll
            for (int c = 0; c < 4; ++c) {
                int rr = 4 * ty + r, cc = 4 * tx + c;
                if (!diag || cc <= rr)
                    Aij[(size_t)rr * 512 + cc] -= acc[r][c];
            }
    }
}

// ---------------------------------------------------------------------------
// fused solve per column: L y = b (fwd, reads LT columns - coalesced),
// L^T z = y (bwd, reads LT rows), then column reductions. LT-only.
// ---------------------------------------------------------------------------
__global__ __launch_bounds__(64) void solve_kernel(const double* __restrict__ U,   // = LT
                                                   const double* __restrict__ Dinv,
                                                   const double* __restrict__ DinvT,
                                                   double* __restrict__ B,
                                                   const float* __restrict__ ys,
                                                   const float* __restrict__ b_p,
                                                   float* __restrict__ out,
                                                   double* __restrict__ kbx,
                                                   double* __restrict__ Sp) {
    const int c = blockIdx.x, lane = threadIdx.x;
    double* col = B + (size_t)c * 512;
    __shared__ double y[512];
    __shared__ double z[512];
    __shared__ double v[64];
    double breg[8];
#pragma unroll
    for (int k = 0; k < 8; ++k) breg[k] = col[64 * k + lane];
    // forward: L[row][j] = U[j][row]; per j one coalesced wave-wide load
    for (int k = 0; k < 8; ++k) {
        double acc = 0.0;
        const int base = 64 * k + lane;
        const int jmax = 64 * k;
        for (int j = 0; j < jmax; j += 8) {
#pragma unroll
            for (int u = 0; u < 8; ++u)
                acc = fma(U[(size_t)(j + u) * 512 + base], y[j + u], acc);
        }
        v[lane] = breg[k] - acc;
        __syncthreads();
        const double* Dk = DinvT + (size_t)k * 4096;
        double yr = 0.0;
#pragma unroll 8
        for (int t = 0; t < 64; ++t) yr = fma(Dk[t * 64 + lane], v[t], yr);
        y[64 * k + lane] = yr;
        __syncthreads();
    }
    // backward: U rows, per-lane streams
    for (int k = 7; k >= 0; --k) {
        const double* row = U + (size_t)(64 * k + lane) * 512;
        double acc = 0.0;
        for (int j = 64 * (k + 1); j < 512; j += 8) {
            double2 l0 = *(const double2*)(row + j + 0);
            double2 l1 = *(const double2*)(row + j + 2);
            double2 l2 = *(const double2*)(row + j + 4);
            double2 l3 = *(const double2*)(row + j + 6);
            acc = fma(l0.x, z[j + 0], acc); acc = fma(l0.y, z[j + 1], acc);
            acc = fma(l1.x, z[j + 2], acc); acc = fma(l1.y, z[j + 3], acc);
            acc = fma(l2.x, z[j + 4], acc); acc = fma(l2.y, z[j + 5], acc);
            acc = fma(l3.x, z[j + 6], acc); acc = fma(l3.y, z[j + 7], acc);
        }
        v[lane] = y[64 * k + lane] - acc;
        __syncthreads();
        const double* Dk = Dinv + (size_t)k * 4096;
        double zr = 0.0;
#pragma unroll 8
        for (int t = 0; t < 64; ++t) zr = fma(Dk[t * 64 + lane], v[t], zr);
        z[64 * k + lane] = zr;
        __syncthreads();
    }
    const double b = (double)b_p[0];
    double s0 = 0.0, s1 = 0.0;
#pragma unroll
    for (int k = 0; k < 8; ++k) {
        int n = 64 * k + lane;
        double zv = z[n];
        col[n] = zv;
        s0 += zv;
        s1 = fma(zv, (double)ys[n] - b, s1);
    }
#pragma unroll
    for (int off = 1; off < 64; off <<= 1) {
        s0 += __shfl_xor(s0, off, 64);
        s1 += __shfl_xor(s1, off, 64);
    }
    if (lane == 0) {
        if (c < 256) { out[c] = (float)(b + s1); kbx[c] = s0; }
        else Sp[0] = s0;
    }
}

// cov[i][j] = Kxx[i][j] - sum_n Z[i][n]*Kox[n][j] + (1-kbx[i])(1-kbx[j])/S
__global__ __launch_bounds__(256) void cov_kernel(const double* __restrict__ Z,
                                                  const float* __restrict__ Kox,
                                                  const float* __restrict__ Kxx,
                                                  const double* __restrict__ kbx,
                                                  const double* __restrict__ Sp,
                                                  float* __restrict__ out) {
    const int bj = blockIdx.x, bi = blockIdx.y;
    const int tx = threadIdx.x & 15, ty = threadIdx.x >> 4;
    const int i = bi * 16 + ty, j = bj * 16 + tx;
    __shared__ double sZ[16][17];
    __shared__ float sK[16][17];
    double acc = 0.0;
    for (int kt = 0; kt < 32; ++kt) {
        sZ[ty][tx] = Z[(size_t)i * 512 + kt * 16 + tx];
        sK[ty][tx] = Kox[(size_t)(kt * 16 + ty) * 256 + j];
        __syncthreads();
#pragma unroll
        for (int t = 0; t < 16; ++t) acc = fma(sZ[ty][t], (double)sK[t][tx], acc);
        __syncthreads();
    }
    const double S = Sp[0];
    const double corr = (1.0 - kbx[i]) * (1.0 - kbx[j]) / S;
    out[(size_t)(1 + i) * 256 + j] = (float)((double)Kxx[(size_t)i * 256 + j] - acc + corr);
}

// ---------------------------------------------------------------------------
extern "C" void kernel_launch(void* const* d_in, const int* in_sizes, int n_in,
                              void* d_out, int out_size, void* d_ws, size_t ws_size,
                              hipStream_t stream) {
    const float* X_test = (const float*)d_in[0];
    const float* A_test = (const float*)d_in[1];
    const float* X_obs  = (const float*)d_in[2];
    const float* A_obs  = (const float*)d_in[3];
    const float* ys     = (const float*)d_in[4];
    const float* rho_p  = (const float*)d_in[5];
    const float* g_p    = (const float*)d_in[6];
    const float* nu_p   = (const float*)d_in[7];
    const float* b_p    = (const float*)d_in[8];
    float* out = (float*)d_out;
    char* ws = (char*)d_ws;

    double* Koo  = (double*)(ws + 0);         // 2,097,152 (stays raw A)
    double* LT   = (double*)(ws + 2097152);   // 2,097,152 (upper-tri = L^T)
    double* Bc   = (double*)(ws + 4194304);   // 1,052,672
    float*  Kox  = (float*) (ws + 5246976);   // 524,288
    float*  Kxx  = (float*) (ws + 5771264);   // 262,144
    float*  s1v  = (float*) (ws + 6033408);   // 1,024
    float*  s2v  = (float*) (ws + 6034432);   // 2,048
    double* kbx  = (double*)(ws + 6036480);   // 2,048
    double* Sp   = (double*)(ws + 6038528);   // 8 (+pad)
    double* Dinv = (double*)(ws + 6039552);   // 262,144
    double* DinvT= (double*)(ws + 6301696);   // 262,144 (end 6,563,840)
    // at arrays live in LT's space (consumed by gram before chol writes LT)
    float*  atT  = (float*)(ws + 2097152);           // 24,576
    float*  atO  = (float*)(ws + 2097152 + 24576);   // 49,152

    self_kernel<<<M + N + 1, 64, 0, stream>>>(X_test, A_test, X_obs, A_obs,
                                              s1v, s2v, atT, atO, Bc);

    gram_kernel<<<dim3(32, 64, 3), 128, 0, stream>>>(X_test, atT, s1v,
                                                     X_obs, atO, s2v,
                                                     rho_p, nu_p, g_p,
                                                     Kox, Kxx, Koo, Bc);

    factor0_kernel<<<1, 256, 0, stream>>>(Koo, LT, Dinv, DinvT);
    for (int p = 0; p < 7; ++p) {
        int nb = (7 - p) * (8 - p) / 2;
        upd_kernel<<<nb, 256, 0, stream>>>(Koo, LT, Dinv, DinvT, p);
    }

    solve_kernel<<<257, 64, 0, stream>>>(LT, Dinv, DinvT, Bc, ys, b_p, out, kbx, Sp);

    cov_kernel<<<dim3(16, 16), 256, 0, stream>>>(Bc, Kox, Kxx, kbx, Sp, out);
}